// Round 12
// baseline (291.786 us; speedup 1.0000x reference)
//
#include <hip/hip_runtime.h>
#include <hip/hip_bf16.h>

#define FIN 256
#define HID 64
#define EMB 2
#define BKB 9            // bucket = dst >> 9 (512 nodes per bucket)
#define BKSZ 512
#define MAXBK 256        // supports N <= 131072
#define NBLK 256         // blocks for binning passes

typedef __bf16 bf16x8 __attribute__((ext_vector_type(8)));
typedef float  f32x16 __attribute__((ext_vector_type(16)));
typedef unsigned short u16x8 __attribute__((ext_vector_type(8)));

// ---- bf16 helpers (RNE) ----
static __device__ __forceinline__ unsigned short f2bf(float f) {
    union { float f; unsigned int u; } v; v.f = f;
    unsigned int u = v.u;
    unsigned int r = (u + 0x7fffu + ((u >> 16) & 1u)) >> 16;
    return (unsigned short)r;
}
static __device__ __forceinline__ float bf2f(unsigned short h) {
    union { unsigned int u; float f; } v; v.u = ((unsigned int)h) << 16;
    return v.f;
}

// ---------------------------------------------------------------------------
// Tiny init: zero bucket cursors + pool accumulators (one block).
__global__ __launch_bounds__(256) void init_small_kernel(
        int* __restrict__ bucketCursor, float* __restrict__ sums, int NBK, int nzero) {
    int tid = threadIdx.x;
    for (int b = tid; b < NBK; b += 256) bucketCursor[b] = 0;
    for (int i = tid; i < nzero; i += 256) sums[i] = 0.f;
}

// ---------------------------------------------------------------------------
// Fused count + reserve + scatter (one kernel, no global scan):
//   LDS hist of my chunk -> one atomicAdd per (block,bucket) reserves a
//   contiguous run in bucket b's fixed-capacity region [b*CAP, (b+1)*CAP)
//   -> scatter packed (src<<9 | dst&511). int4 vector loads.
__global__ __launch_bounds__(256) void bin_scatter_kernel(
        const int* __restrict__ src, const int* __restrict__ dst,
        int* __restrict__ bucketCursor, unsigned* __restrict__ ebuf,
        int E, int chunk, int NBK, int CAP) {
    __shared__ int hist[MAXBK];
    __shared__ int cur[MAXBK];
    int tid = threadIdx.x;
    for (int b = tid; b < NBK; b += 256) hist[b] = 0;
    __syncthreads();
    int e0 = blockIdx.x * chunk, e1 = min(e0 + chunk, E);
    if (e0 < e1) {
        const int4* d4 = (const int4*)(dst + e0);
        int nv = (e1 - e0) >> 2;
        for (int i = tid; i < nv; i += 256) {
            int4 v = d4[i];
            atomicAdd(&hist[v.x >> BKB], 1);
            atomicAdd(&hist[v.y >> BKB], 1);
            atomicAdd(&hist[v.z >> BKB], 1);
            atomicAdd(&hist[v.w >> BKB], 1);
        }
        for (int i = e0 + (nv << 2) + tid; i < e1; i += 256)
            atomicAdd(&hist[dst[i] >> BKB], 1);
    }
    __syncthreads();
    // reserve contiguous runs (one device atomic per non-empty bucket)
    for (int b = tid; b < NBK; b += 256) {
        int h = hist[b];
        int base = (h > 0) ? atomicAdd(&bucketCursor[b], h) : 0;
        cur[b] = b * CAP + base;
    }
    __syncthreads();
    if (e0 >= e1) return;
    const int4* s4 = (const int4*)(src + e0);
    const int4* d4 = (const int4*)(dst + e0);
    int nv = (e1 - e0) >> 2;
    for (int i = tid; i < nv; i += 256) {
        int4 sv = s4[i], dv = d4[i];
        int b0 = dv.x >> BKB;
        int p0 = atomicAdd(&cur[b0], 1);
        ebuf[p0] = ((unsigned)sv.x << BKB) | (unsigned)(dv.x & (BKSZ - 1));
        int b1 = dv.y >> BKB;
        int p1 = atomicAdd(&cur[b1], 1);
        ebuf[p1] = ((unsigned)sv.y << BKB) | (unsigned)(dv.y & (BKSZ - 1));
        int b2 = dv.z >> BKB;
        int p2 = atomicAdd(&cur[b2], 1);
        ebuf[p2] = ((unsigned)sv.z << BKB) | (unsigned)(dv.z & (BKSZ - 1));
        int b3 = dv.w >> BKB;
        int p3 = atomicAdd(&cur[b3], 1);
        ebuf[p3] = ((unsigned)sv.w << BKB) | (unsigned)(dv.w & (BKSZ - 1));
    }
    for (int i = e0 + (nv << 2) + tid; i < e1; i += 256) {
        int s = src[i], d = dst[i];
        int b = d >> BKB;
        int pos = atomicAdd(&cur[b], 1);
        ebuf[pos] = ((unsigned)s << BKB) | (unsigned)(d & (BKSZ - 1));
    }
}

// Pass B: one block per bucket -> degree/dinv/rowptr{start,end} + bucket-local
// CSR scatter. Bucket region = [b*CAP, b*CAP + bucketCursor[b]).
__global__ __launch_bounds__(256) void build_kernel(
        const unsigned* __restrict__ ebuf, const int* __restrict__ bucketCursor,
        int2* __restrict__ rowptr2, float* __restrict__ dinv, int* __restrict__ csr,
        int N, int CAP) {
    __shared__ int hist[BKSZ];
    __shared__ int scanb[256];
    __shared__ int cur[BKSZ];
    const int b = blockIdx.x, tid = threadIdx.x;
    const int r0 = b * CAP;
    const int r1 = r0 + bucketCursor[b];
    const int nb0 = b * BKSZ;

    hist[tid] = 0; hist[tid + 256] = 0;
    __syncthreads();
    for (int i = r0 + tid; i < r1; i += 256)
        atomicAdd(&hist[ebuf[i] & (BKSZ - 1u)], 1);
    __syncthreads();

    int h0 = hist[2 * tid], h1 = hist[2 * tid + 1];
    if (nb0 + 2 * tid < N)     dinv[nb0 + 2 * tid]     = rsqrtf((float)h0 + 1.f);
    if (nb0 + 2 * tid + 1 < N) dinv[nb0 + 2 * tid + 1] = rsqrtf((float)h1 + 1.f);
    scanb[tid] = h0 + h1;
    __syncthreads();
    for (int off = 1; off < 256; off <<= 1) {
        int t = (tid >= off) ? scanb[tid - off] : 0;
        __syncthreads();
        scanb[tid] += t;
        __syncthreads();
    }
    int base0 = scanb[tid] - (h0 + h1);
    int o0 = base0, o1 = base0 + h0;
    cur[2 * tid] = o0; cur[2 * tid + 1] = o1;
    if (nb0 + 2 * tid < N)
        rowptr2[nb0 + 2 * tid]     = make_int2(r0 + o0, r0 + o0 + h0);
    if (nb0 + 2 * tid + 1 < N)
        rowptr2[nb0 + 2 * tid + 1] = make_int2(r0 + o1, r0 + o1 + h1);
    __syncthreads();
    for (int i = r0 + tid; i < r1; i += 256) {
        unsigned u = ebuf[i];
        int loc = (int)(u & (BKSZ - 1u));
        int p = atomicAdd(&cur[loc], 1);
        csr[r0 + p] = (int)(u >> BKB);
    }
}

// ---------------------------------------------------------------------------
// h1' = dinv * (x @ W1) via MFMA (bf16 hi/lo split: xh*wh + xh*wl + xl*wh).
// Block = 64-node x 64-feat tile, 4 waves = four 32x32 quadrants. bf16 store.
__global__ __launch_bounds__(256) void gemm1_kernel(
        const float* __restrict__ x, const float* __restrict__ W,
        const float* __restrict__ dinv, unsigned short* __restrict__ h1b, int N) {
    __shared__ __align__(16) __bf16 A_hi[2 * 4 * 64 * 8];
    __shared__ __align__(16) __bf16 A_lo[2 * 4 * 64 * 8];
    __shared__ __align__(16) __bf16 B_hi[2 * 4 * 64 * 8];
    __shared__ __align__(16) __bf16 B_lo[2 * 4 * 64 * 8];

    const int tid = threadIdx.x;
    const int base = blockIdx.x * 64;
    const int w = tid >> 6;
    const int l = tid & 63;
    const int mg = w >> 1, ng = w & 1;

    f32x16 acc = {};

    const int r  = tid & 63;
    const int ks = tid >> 6;
    const int rl = r & 31, rh = r >> 5;

    for (int ch = 0; ch < 4; ++ch) {
        const int ck0 = ch * 64;
        __syncthreads();
        {
            int row = base + r;
            float f[16];
            if (row < N) {
                const float* xp = &x[(size_t)row * FIN + ck0 + ks * 16];
                float4 v0 = *(const float4*)(xp + 0);
                float4 v1 = *(const float4*)(xp + 4);
                float4 v2 = *(const float4*)(xp + 8);
                float4 v3 = *(const float4*)(xp + 12);
                f[0]=v0.x; f[1]=v0.y; f[2]=v0.z; f[3]=v0.w;
                f[4]=v1.x; f[5]=v1.y; f[6]=v1.z; f[7]=v1.w;
                f[8]=v2.x; f[9]=v2.y; f[10]=v2.z; f[11]=v2.w;
                f[12]=v3.x; f[13]=v3.y; f[14]=v3.z; f[15]=v3.w;
            } else {
                #pragma unroll
                for (int q = 0; q < 16; ++q) f[q] = 0.f;
            }
            bf16x8 ha, hb, la, lb;
            #pragma unroll
            for (int q = 0; q < 8; ++q) {
                __bf16 h0 = (__bf16)f[q];
                ha[q] = h0; la[q] = (__bf16)(f[q] - (float)h0);
                __bf16 h1v = (__bf16)f[q + 8];
                hb[q] = h1v; lb[q] = (__bf16)(f[q + 8] - (float)h1v);
            }
            int ra = ((rh * 4 + ks) * 64 + rl) * 8;
            int rb = ((rh * 4 + ks) * 64 + 32 + rl) * 8;
            *(bf16x8*)&A_hi[ra] = ha; *(bf16x8*)&A_hi[rb] = hb;
            *(bf16x8*)&A_lo[ra] = la; *(bf16x8*)&A_lo[rb] = lb;
        }
        {
            const float* wp = &W[(size_t)(ck0 + ks * 16) * HID + r];
            float f[16];
            #pragma unroll
            for (int q = 0; q < 16; ++q) f[q] = wp[q * HID];
            bf16x8 ha, hb, la, lb;
            #pragma unroll
            for (int q = 0; q < 8; ++q) {
                __bf16 h0 = (__bf16)f[q];
                ha[q] = h0; la[q] = (__bf16)(f[q] - (float)h0);
                __bf16 h1v = (__bf16)f[q + 8];
                hb[q] = h1v; lb[q] = (__bf16)(f[q + 8] - (float)h1v);
            }
            int ra = ((rh * 4 + ks) * 64 + rl) * 8;
            int rb = ((rh * 4 + ks) * 64 + 32 + rl) * 8;
            *(bf16x8*)&B_hi[ra] = ha; *(bf16x8*)&B_hi[rb] = hb;
            *(bf16x8*)&B_lo[ra] = la; *(bf16x8*)&B_lo[rb] = lb;
        }
        __syncthreads();

        #pragma unroll
        for (int s = 0; s < 4; ++s) {
            bf16x8 a_h = *(const bf16x8*)&A_hi[((mg * 4 + s) * 64 + l) * 8];
            bf16x8 a_l = *(const bf16x8*)&A_lo[((mg * 4 + s) * 64 + l) * 8];
            bf16x8 b_h = *(const bf16x8*)&B_hi[((ng * 4 + s) * 64 + l) * 8];
            bf16x8 b_l = *(const bf16x8*)&B_lo[((ng * 4 + s) * 64 + l) * 8];
            acc = __builtin_amdgcn_mfma_f32_32x32x16_bf16(a_h, b_h, acc, 0, 0, 0);
            acc = __builtin_amdgcn_mfma_f32_32x32x16_bf16(a_h, b_l, acc, 0, 0, 0);
            acc = __builtin_amdgcn_mfma_f32_32x32x16_bf16(a_l, b_h, acc, 0, 0, 0);
        }
    }

    const int col = l & 31;
    const int rbase = 4 * (l >> 5);
    #pragma unroll
    for (int reg = 0; reg < 16; ++reg) {
        int row = (reg & 3) + 8 * (reg >> 2) + rbase;
        int node = base + mg * 32 + row;
        if (node < N)
            h1b[(size_t)node * HID + ng * 32 + col] = f2bf(acc[reg] * dinv[node]);
    }
}

// ---------------------------------------------------------------------------
// Fused layer-1 CSR gather (pure sum of pre-scaled h1') + b1 + ReLU + (64->2).
// 8 nodes per wave: 8 lanes/node, lane = 8 feats (ushort8 = 16 B/lane gather).
__global__ __launch_bounds__(256) void agg1_layer2_kernel(
        const int2* __restrict__ rowptr2, const int* __restrict__ csr,
        const unsigned short* __restrict__ h1b,
        const float* __restrict__ dinv, const float* __restrict__ b1,
        const float* __restrict__ W2, float* __restrict__ h2, int N) {
    long t = (long)blockIdx.x * blockDim.x + threadIdx.x;
    int n = (int)(t >> 3);
    int li = threadIdx.x & 7;
    if (n >= N) return;
    const u16x8* h18 = (const u16x8*)h1b;    // row = 8 vectors x 8 feats

    float di = dinv[n];
    u16x8 sl = h18[(size_t)n * 8 + li];      // self term (h1' pre-scaled)
    float v[8];
    #pragma unroll
    for (int k = 0; k < 8; ++k) v[k] = bf2f(sl[k]);

    int2 rp = rowptr2[n];
    int j = rp.x, j1 = rp.y;
    for (; j + 3 < j1; j += 4) {
        int s0 = csr[j], s1 = csr[j + 1], s2 = csr[j + 2], s3 = csr[j + 3];
        u16x8 g0 = h18[(size_t)s0 * 8 + li];
        u16x8 g1 = h18[(size_t)s1 * 8 + li];
        u16x8 g2 = h18[(size_t)s2 * 8 + li];
        u16x8 g3 = h18[(size_t)s3 * 8 + li];
        #pragma unroll
        for (int k = 0; k < 8; ++k)
            v[k] += bf2f(g0[k]) + bf2f(g1[k]) + bf2f(g2[k]) + bf2f(g3[k]);
    }
    for (; j < j1; ++j) {
        u16x8 g = h18[(size_t)csr[j] * 8 + li];
        #pragma unroll
        for (int k = 0; k < 8; ++k) v[k] += bf2f(g[k]);
    }

    // bias + ReLU (feats f = li*8 + k)
    const float4 ba = *(const float4*)&b1[li * 8];
    const float4 bb = *(const float4*)&b1[li * 8 + 4];
    v[0] = fmaxf(di * v[0] + ba.x, 0.f); v[1] = fmaxf(di * v[1] + ba.y, 0.f);
    v[2] = fmaxf(di * v[2] + ba.z, 0.f); v[3] = fmaxf(di * v[3] + ba.w, 0.f);
    v[4] = fmaxf(di * v[4] + bb.x, 0.f); v[5] = fmaxf(di * v[5] + bb.y, 0.f);
    v[6] = fmaxf(di * v[6] + bb.z, 0.f); v[7] = fmaxf(di * v[7] + bb.w, 0.f);

    // W2 rows li*8 .. li*8+7 (each row = 2 floats): 4 float4 loads
    const float4* W24 = (const float4*)W2;
    float r0 = 0.f, r1 = 0.f;
    #pragma unroll
    for (int k = 0; k < 4; ++k) {
        float4 wq = W24[li * 4 + k];         // rows li*8+2k (x,y), li*8+2k+1 (z,w)
        r0 += v[2 * k] * wq.x + v[2 * k + 1] * wq.z;
        r1 += v[2 * k] * wq.y + v[2 * k + 1] * wq.w;
    }
    #pragma unroll
    for (int off = 1; off < 8; off <<= 1) {
        r0 += __shfl_xor(r0, off);
        r1 += __shfl_xor(r1, off);
    }
    if (li == 0) *(float2*)&h2[(size_t)n * EMB] = make_float2(r0 * di, r1 * di);  // h2' = dinv*h2
}

// ---------------------------------------------------------------------------
// Fused layer-2 CSR gather (pure sum of h2') + b2 + global mean pool.
__global__ __launch_bounds__(256) void agg2_pool_kernel(
        const int2* __restrict__ rowptr2, const int* __restrict__ csr,
        const float* __restrict__ h2,
        const float* __restrict__ dinv, const float* __restrict__ b2,
        const int* __restrict__ batch,
        float* __restrict__ sums, float* __restrict__ cntf, int N) {
    int n = blockIdx.x * blockDim.x + threadIdx.x;
    int lane = threadIdx.x & 63;
    const float2* h2v = (const float2*)h2;
    float v0 = 0.f, v1 = 0.f, c = 0.f;
    int g = -1;
    if (n < N) {
        float di = dinv[n];
        float2 hs = h2v[n];
        v0 = hs.x; v1 = hs.y;
        int2 rp = rowptr2[n];
        int j = rp.x, j1 = rp.y;
        for (; j + 3 < j1; j += 4) {
            int s0 = csr[j], s1 = csr[j + 1], s2 = csr[j + 2], s3 = csr[j + 3];
            float2 a = h2v[s0], b = h2v[s1], cc = h2v[s2], d = h2v[s3];
            v0 += a.x + b.x + cc.x + d.x;
            v1 += a.y + b.y + cc.y + d.y;
        }
        for (; j < j1; ++j) {
            float2 hv = h2v[csr[j]];
            v0 += hv.x; v1 += hv.y;
        }
        v0 = di * v0 + b2[0];
        v1 = di * v1 + b2[1];
        g = batch[n];
        c = 1.f;
    }
    #pragma unroll
    for (int off = 1; off < 64; off <<= 1) {
        int gg = __shfl_up(g, off);
        float t0 = __shfl_up(v0, off);
        float t1 = __shfl_up(v1, off);
        float tc = __shfl_up(c, off);
        if (lane >= off && gg == g) { v0 += t0; v1 += t1; c += tc; }
    }
    int gn = __shfl_down(g, 1);
    if (g >= 0 && (lane == 63 || gn != g)) {
        atomicAdd(&sums[g * EMB + 0], v0);
        atomicAdd(&sums[g * EMB + 1], v1);
        atomicAdd(&cntf[g], c);
    }
}

__global__ void final_kernel(const float* __restrict__ sums, const float* __restrict__ cntf,
                             float* __restrict__ out, int G) {
    int g = blockIdx.x * blockDim.x + threadIdx.x;
    if (g >= G) return;
    float c = fmaxf(cntf[g], 1.0f);
    out[g * EMB + 0] = sums[g * EMB + 0] / c;
    out[g * EMB + 1] = sums[g * EMB + 1] / c;
}

// ---------------------------------------------------------------------------
extern "C" void kernel_launch(void* const* d_in, const int* in_sizes, int n_in,
                              void* d_out, int out_size, void* d_ws, size_t ws_size,
                              hipStream_t stream) {
    const float* x     = (const float*)d_in[0];
    const int*   ei    = (const int*)d_in[1];
    const int*   batch = (const int*)d_in[2];
    const float* W1    = (const float*)d_in[3];
    const float* b1    = (const float*)d_in[4];
    const float* W2    = (const float*)d_in[5];
    const float* b2    = (const float*)d_in[6];
    float* out = (float*)d_out;

    const int N = in_sizes[0] / FIN;   // 100000
    const int E = in_sizes[1] / 2;     // 1600000
    const int G = out_size / EMB;      // 512
    const int* src = ei;
    const int* dst = ei + E;

    const int NBK = (N + BKSZ - 1) / BKSZ;                    // 196 coarse buckets
    const int chunk = (((E + NBLK - 1) / NBLK) + 3) & ~3;     // x4 -> 16B-aligned slices
    const int CAP = ((2 * E / NBK) + 3) & ~3;                 // 2x mean bucket size

    // ---- workspace layout (16 B aligned chunks) ----
    char* p = (char*)d_ws;
    auto take = [&](size_t bytes) { char* r = p; p += (bytes + 15) & ~(size_t)15; return r; };
    int*      bucketCursor = (int*)take(sizeof(int) * NBK);
    unsigned* ebuf   = (unsigned*)take(sizeof(unsigned) * (size_t)NBK * CAP);
    int*      csr    = (int*)take(sizeof(int) * (size_t)NBK * CAP);
    int2*     rowptr2= (int2*)take(sizeof(int2) * N);
    float*    dinv   = (float*)take(sizeof(float) * N);
    unsigned short* h1b = (unsigned short*)take(sizeof(unsigned short) * (size_t)N * HID);
    float*    h2     = (float*)take(sizeof(float) * (size_t)N * EMB);
    float*    sums   = (float*)take(sizeof(float) * G * EMB);
    float*    cntf   = (float*)take(sizeof(float) * G);

    // 1. CSR build: init -> fused count/reserve/scatter -> per-bucket build
    init_small_kernel<<<1, 256, 0, stream>>>(bucketCursor, sums, NBK, 3 * G);
    bin_scatter_kernel<<<NBLK, 256, 0, stream>>>(src, dst, bucketCursor, ebuf, E, chunk, NBK, CAP);
    build_kernel<<<NBK, 256, 0, stream>>>(ebuf, bucketCursor, rowptr2, dinv, csr, N, CAP);
    // 2. h1' = dinv * (x @ W1)  (MFMA, bf16 out, row-major)
    gemm1_kernel<<<(N + 63) / 64, 256, 0, stream>>>(x, W1, dinv, h1b, N);
    // 3. fused agg1 + relu + W2 -> h2' = dinv * h2  (8 nodes/wave, 16 B/lane)
    agg1_layer2_kernel<<<(int)(((long)N * 8 + 255) / 256), 256, 0, stream>>>(
        rowptr2, csr, h1b, dinv, b1, W2, h2, N);
    // 4. fused agg2 + pool, then finalize
    agg2_pool_kernel<<<(N + 255) / 256, 256, 0, stream>>>(
        rowptr2, csr, h2, dinv, b2, batch, sums, cntf, N);
    final_kernel<<<(G + 255) / 256, 256, 0, stream>>>(sums, cntf, out, G);
}